// Round 1
// baseline (97.802 us; speedup 1.0000x reference)
//
#include <hip/hip_runtime.h>

// MiniBatchDiscrimination fused kernel for MI355X (gfx950).
// x: [32,16,16,256] f32, T: [256,64,8] f32, out: [32,16,16,320] f32
// One block per (h,w) pixel: GEMM 32x512x256 in registers, M tile in LDS,
// pairwise exp(-L1) phase out of LDS. No fp32 MFMA on CDNA4 -> vector FMA.

namespace {
constexpr int kN = 32;        // batch
constexpr int kHW = 256;      // H*W
constexpr int kF = 256;       // features
constexpr int kB = 64;        // discrimination kernels
constexpr int kC = 8;         // kernel dims
constexpr int kT = kB * kC;   // 512
constexpr int kChunk = 64;    // k-chunk for x staging
constexpr int kOutRow = kF + kB;  // 320
}

__global__ __launch_bounds__(512, 2)
void mbd_fused(const float* __restrict__ x, const float* __restrict__ Tm,
               float* __restrict__ out) {
  // 64 KB LDS: during GEMM, first 2048 floats hold the x k-chunk [32][64];
  // afterwards the whole array holds M [32][512].
  __shared__ float lds[kN * kT];
  const int hw = blockIdx.x;
  const int tid = threadIdx.x;

  // GEMM thread tile: 8 n-rows x 4 t-cols per thread.
  const int t0 = (tid & 127) * 4;   // 0..508
  const int n0 = (tid >> 7) * 8;    // 0,8,16,24  (wave-uniform)

  float acc[8][4];
#pragma unroll
  for (int i = 0; i < 8; ++i)
#pragma unroll
    for (int j = 0; j < 4; ++j) acc[i][j] = 0.f;

  const float4* x4 = (const float4*)x;
  float4* out4 = (float4*)out;
  float4* xs4 = (float4*)lds;

  for (int kc = 0; kc < kF / kChunk; ++kc) {
    // Stage x chunk [32][64] into LDS; also pass x through to out.
    {
      const int v = tid;            // 0..511, one float4 each (2048 floats)
      const int n = v >> 4;         // 0..31
      const int f4 = v & 15;        // float4 index within chunk
      float4 val = x4[n * (kHW * kF / 4) + hw * (kF / 4) + kc * 16 + f4];
      xs4[v] = val;
      out4[(n * kHW + hw) * (kOutRow / 4) + kc * 16 + f4] = val;
    }
    __syncthreads();

    const float* Tk = Tm + (size_t)kc * kChunk * kT;
#pragma unroll 4
    for (int k = 0; k < kChunk; ++k) {
      float4 bv = *(const float4*)(Tk + k * kT + t0);
#pragma unroll
      for (int i = 0; i < 8; ++i) {
        float a = lds[(n0 + i) * kChunk + k];
        acc[i][0] = fmaf(a, bv.x, acc[i][0]);
        acc[i][1] = fmaf(a, bv.y, acc[i][1]);
        acc[i][2] = fmaf(a, bv.z, acc[i][2]);
        acc[i][3] = fmaf(a, bv.w, acc[i][3]);
      }
    }
    __syncthreads();  // protect xs chunk before next staging / M write
  }

  // Write M tile [32][512] into LDS (overwrites x-chunk region; all reads done).
#pragma unroll
  for (int i = 0; i < 8; ++i) {
    *(float4*)&lds[(n0 + i) * kT + t0] =
        make_float4(acc[i][0], acc[i][1], acc[i][2], acc[i][3]);
  }
  __syncthreads();

  // Pairwise phase: 2048 tasks (b,i); 4 per thread.
  // Lanes 0..31 of a half-wave share b -> Mj reads are same-address broadcast.
#pragma unroll
  for (int s = 0; s < 4; ++s) {
    const int task = tid + s * 512;   // 0..2047
    const int b = task >> 5;          // 0..63
    const int i = task & 31;          // 0..31
    const float* Mi = &lds[i * kT + b * kC];
    float mi[8];
#pragma unroll
    for (int c = 0; c < 8; ++c) mi[c] = Mi[c];
    float ob = 0.f;
#pragma unroll 4
    for (int j = 0; j < kN; ++j) {
      const float* Mj = &lds[j * kT + b * kC];
      float nrm = 0.f;
#pragma unroll
      for (int c = 0; c < 8; ++c) nrm += fabsf(mi[c] - Mj[c]);
      ob += __expf(-nrm);
    }
    out[(size_t)(i * kHW + hw) * kOutRow + kF + b] = ob;
  }
}

extern "C" void kernel_launch(void* const* d_in, const int* in_sizes, int n_in,
                              void* d_out, int out_size, void* d_ws, size_t ws_size,
                              hipStream_t stream) {
  const float* x = (const float*)d_in[0];   // [32,16,16,256]
  const float* T = (const float*)d_in[1];   // [256,64,8]
  float* out = (float*)d_out;               // [32,16,16,320]
  (void)in_sizes; (void)n_in; (void)out_size; (void)d_ws; (void)ws_size;
  mbd_fused<<<dim3(kHW), dim3(512), 0, stream>>>(x, T, out);
}